// Round 1
// baseline (509.486 us; speedup 1.0000x reference)
//
#include <hip/hip_runtime.h>
#include <math.h>

// CosFace-style loss:
//   num_i   = S*(x[i,y_i] - M)
//   sum_i   = sum_j exp(S*x[i,j])
//   denom_i = exp(num_i) + (sum_i - exp(S*x[i,y_i]))
//   L_i     = (num_i - log(denom_i)) / S
//   out     = -mean_i(L_i)
// Memory-bound: 400 MB read of x, roofline ~64 us @ 6.3 TB/s.

#define SCALE 64.0f
#define MARGIN 0.35f

__device__ __forceinline__ double block_reduce_d(double v) {
    // wave64 butterfly-down, then cross-wave via LDS (256 threads = 4 waves)
    #pragma unroll
    for (int off = 32; off > 0; off >>= 1) v += __shfl_down(v, off, 64);
    __shared__ double s[4];
    const int lane = threadIdx.x & 63;
    const int w    = threadIdx.x >> 6;
    if (lane == 0) s[w] = v;
    __syncthreads();
    if (w == 0) {
        v = (lane < 4) ? s[lane] : 0.0;
        v += __shfl_down(v, 2, 64);
        v += __shfl_down(v, 1, 64);
    }
    return v;  // valid in thread 0
}

__global__ __launch_bounds__(256) void row_loss_kernel(
    const float* __restrict__ x, const int* __restrict__ label,
    double* __restrict__ row_L, int C)
{
    const int row = blockIdx.x;
    const float* __restrict__ xr = x + (size_t)row * (size_t)C;
    const int tid = threadIdx.x;

    const int n4 = C >> 2;
    const float4* __restrict__ x4 = (const float4*)xr;

    double acc = 0.0;
    int v = tid;
    // unrolled x4: 4 independent float4 loads in flight per wave
    for (; v + 3 * 256 < n4; v += 4 * 256) {
        float4 a = x4[v];
        float4 b = x4[v + 256];
        float4 c = x4[v + 512];
        float4 d = x4[v + 768];
        float s0 = __expf(SCALE * a.x) + __expf(SCALE * a.y) +
                   __expf(SCALE * a.z) + __expf(SCALE * a.w);
        float s1 = __expf(SCALE * b.x) + __expf(SCALE * b.y) +
                   __expf(SCALE * b.z) + __expf(SCALE * b.w);
        float s2 = __expf(SCALE * c.x) + __expf(SCALE * c.y) +
                   __expf(SCALE * c.z) + __expf(SCALE * c.w);
        float s3 = __expf(SCALE * d.x) + __expf(SCALE * d.y) +
                   __expf(SCALE * d.z) + __expf(SCALE * d.w);
        acc += (double)(s0 + s1) + (double)(s2 + s3);
    }
    for (; v < n4; v += 256) {
        float4 a = x4[v];
        float s0 = __expf(SCALE * a.x) + __expf(SCALE * a.y) +
                   __expf(SCALE * a.z) + __expf(SCALE * a.w);
        acc += (double)s0;
    }
    // scalar tail if C % 4 != 0
    for (int j = (n4 << 2) + tid; j < C; j += 256)
        acc += (double)__expf(SCALE * xr[j]);

    double row_sum = block_reduce_d(acc);

    if (tid == 0) {
        const double xy  = (double)xr[label[row]];
        const double num = 64.0 * (xy - 0.35);
        const double exy = exp(64.0 * xy);
        const double sum_excl = row_sum - exy;     // fp64: cancellation-safe
        const double denom = exp(num) + sum_excl;
        const double L = (num - log(denom)) / 64.0;
        row_L[row] = L;
    }
}

__global__ __launch_bounds__(256) void final_reduce_kernel(
    const double* __restrict__ row_L, float* __restrict__ out, int B)
{
    double acc = 0.0;
    for (int i = threadIdx.x; i < B; i += 256) acc += row_L[i];
    double total = block_reduce_d(acc);
    if (threadIdx.x == 0) out[0] = (float)(-total / (double)B);
}

extern "C" void kernel_launch(void* const* d_in, const int* in_sizes, int n_in,
                              void* d_out, int out_size, void* d_ws, size_t ws_size,
                              hipStream_t stream) {
    const float* x     = (const float*)d_in[0];
    const int*   label = (const int*)d_in[1];
    const int B = in_sizes[1];
    const int C = in_sizes[0] / B;

    double* row_L = (double*)d_ws;  // B doubles = 8 KB scratch

    row_loss_kernel<<<B, 256, 0, stream>>>(x, label, row_L, C);
    final_reduce_kernel<<<1, 256, 0, stream>>>(row_L, (float*)d_out, B);
}